// Round 2
// baseline (5241.816 us; speedup 1.0000x reference)
//
#include <hip/hip_runtime.h>
#include <math.h>

// ============================================================================
// RSSM forward on MI355X.
// Round 5: 4x the fill concurrency. R4 counters: rssm_rnn 4280us, 33.7us/step
// == 5.5MB/step / 167GB/s exactly -> the loop drains its L2-fill traffic at a
// concurrency-limited 167GB/s (only 32 CUs busy, Occupancy 6.2%). Row-split
// the persistent recurrence into 128 blocks x 4 batch rows (was 32 x 16):
// identical weight-load/MFMA sequence per block (MFMA rows are independent, so
// padded rows 4..15 are harmless garbage), 4x the blocks -> 4x outstanding
// misses -> fill BW scales. Global loads on padded rows are clamped, stores
// predicated; kept-row arithmetic is bit-identical (absmax unchanged).
// ============================================================================

using v8s   = __attribute__((ext_vector_type(8))) short;
using f32x4 = __attribute__((ext_vector_type(4))) float;

#define BN   512
#define TN   128
#define LATN 128

#define ROWS 4              // batch rows per persistent block
#define NBLK (BN/ROWS)      // 128 persistent blocks

#define AB_S 264   // 256-col LDS activation stride (shorts)
#define SA_S 136   // 128-col stride

// pre-shuffled weight tile bases (1 tile = 16n x 32k bf16 = 1KB = 512 shorts)
#define OBS1_T 0
#define OBS2_T 256
#define PO1O_T 384
#define PO1H_T 512
#define GINS_T 640
#define IH_T   704
#define HH_T   1088
#define PR1_T  1472
#define PR2_T  1600
#define PRM_T  1728
#define PRV_T  1792
#define PO2_T  1856
#define POM_T  1984
#define POV_T  2048
#define TOT_TILES 2112

#define B1_BYTES 33554432UL          // 65536 x 256 bf16
#define KL_OFF   8388608UL           // states elements (512*128*128)

__device__ __forceinline__ unsigned short f2bf(float f){
  union { float f; unsigned u; } v; v.f = f;
  unsigned u = v.u + 0x7fffu + ((v.u >> 16) & 1u);   // RNE
  return (unsigned short)(u >> 16);
}
__device__ __forceinline__ float bf2f(unsigned short s){
  union { unsigned u; float f; } v; v.u = ((unsigned)s) << 16; return v.f;
}
__device__ __forceinline__ float sigm(float x){ return 1.f / (1.f + __expf(-x)); }
__device__ __forceinline__ float tanhx(float x){ return 1.f - 2.f/(__expf(2.f*x) + 1.f); }

#define MFMA16(a,b,c) __builtin_amdgcn_mfma_f32_16x16x32_bf16((a),(b),(c),0,0,0)
#define LDB(tIdx) (*(const v8s*)(wt + ((size_t)(tIdx))*512 + lane*8))

// ---------------------------------------------------------------------------
// Weight shuffle: f32 (N,K) row-major -> bf16 fragment-linear tiles.
// ---------------------------------------------------------------------------
struct ShufArgs {
  const float* src[14];
  int stride[14], coloff[14], ktiles[14], tbase[14], tcnt[14];
};

__global__ __launch_bounds__(64) void shuffle_w(ShufArgs sa, unsigned short* __restrict__ wt)
{
  int tile = blockIdx.x;
  int s = 0;
  while (tile >= sa.tbase[s] + sa.tcnt[s]) s++;
  int lt = tile - sa.tbase[s];
  int kt = lt % sa.ktiles[s];
  int nt = lt / sa.ktiles[s];
  int l  = threadIdx.x;
  int n  = nt*16 + (l & 15);
  int k  = sa.coloff[s] + kt*32 + (l >> 4)*8;
  const float* sp = sa.src[s] + (size_t)n * sa.stride[s] + k;
  unsigned short* dp = wt + (size_t)tile*512 + (size_t)l*8;
  #pragma unroll
  for (int j = 0; j < 8; j++) dp[j] = f2bf(sp[j]);
}

// ---------------------------------------------------------------------------
// Parallel GEMM for obs MLP / po1_o precompute.
// ---------------------------------------------------------------------------
__global__ __launch_bounds__(256) void big_gemm(
    const void* __restrict__ Ain, int aIsF32, int K,
    const unsigned short* __restrict__ wt, int tbase,
    const float* __restrict__ bias, int doRelu,
    unsigned short* __restrict__ outB)
{
  __shared__ unsigned short AL[64*AB_S];
  int tid = threadIdx.x, lane = tid & 63, wv = tid >> 6;
  int q = lane >> 4, c16 = lane & 15;
  size_t row0 = (size_t)blockIdx.x * 64;

  f32x4 acc[16];
  #pragma unroll
  for (int nt = 0; nt < 16; nt++) acc[nt] = (f32x4){0.f,0.f,0.f,0.f};

  int nchunk = K >> 8;
  int ktT    = K >> 5;
  for (int cc = 0; cc < nchunk; cc++){
    int r = tid >> 2, c0 = (tid & 3) * 64;
    if (aIsF32){
      const float* A = (const float*)Ain + (row0 + r) * (size_t)K + (size_t)cc*256 + c0;
      #pragma unroll
      for (int ii = 0; ii < 16; ii++){
        float4 x = ((const float4*)A)[ii];
        ushort4 o;
        o.x = f2bf(x.x); o.y = f2bf(x.y); o.z = f2bf(x.z); o.w = f2bf(x.w);
        *(ushort4*)&AL[r*AB_S + c0 + ii*4] = o;
      }
    } else {
      const unsigned short* A = (const unsigned short*)Ain + (row0 + r)*256 + c0;
      #pragma unroll
      for (int ii = 0; ii < 8; ii++)
        *(v8s*)&AL[r*AB_S + c0 + ii*8] = *(const v8s*)(A + ii*8);
    }
    __syncthreads();
    const unsigned short* myA = &AL[wv*16*AB_S];
    #pragma unroll
    for (int kt = 0; kt < 8; kt++){
      v8s af = *(const v8s*)&myA[c16*AB_S + kt*32 + q*8];
      #pragma unroll
      for (int nt = 0; nt < 16; nt++){
        v8s bf = *(const v8s*)(wt + ((size_t)(tbase + nt*ktT + cc*8 + kt))*512 + lane*8);
        acc[nt] = MFMA16(af, bf, acc[nt]);
      }
    }
    __syncthreads();
  }
  #pragma unroll
  for (int nt = 0; nt < 16; nt++){
    int col = nt*16 + c16;
    float b = bias[col];
    #pragma unroll
    for (int i = 0; i < 4; i++){
      float v = acc[nt][i] + b;
      if (doRelu) v = fmaxf(v, 0.f);
      outB[(row0 + wv*16 + q*4 + i)*256 + col] = f2bf(v);
    }
  }
}

// ---------------------------------------------------------------------------
// Stage helpers: 16 rows x 256 cols, 16 waves; wave wv owns nt = wv.
// All weight tiles for the stage are loaded into registers (wf[8]) BEFORE
// the MFMA chain so 8 loads are in flight per wave.
// ---------------------------------------------------------------------------
__device__ __forceinline__ void stage256(
    const unsigned short* __restrict__ inA,
    const unsigned short* __restrict__ wt, int tbase,
    const float* __restrict__ bias,
    unsigned short* __restrict__ outA, int lane, int wv)
{
  int q = lane >> 4, c16 = lane & 15;
  v8s wf[8];
  #pragma unroll
  for (int kt = 0; kt < 8; kt++) wf[kt] = LDB(tbase + wv*8 + kt);
  v8s af[8];
  #pragma unroll
  for (int kt = 0; kt < 8; kt++) af[kt] = *(const v8s*)&inA[c16*AB_S + kt*32 + q*8];
  f32x4 acc = (f32x4){0.f,0.f,0.f,0.f};
  #pragma unroll
  for (int kt = 0; kt < 8; kt++) acc = MFMA16(af[kt], wf[kt], acc);
  int col = wv*16 + c16;
  float b = bias[col];
  #pragma unroll
  for (int i = 0; i < 4; i++)
    outA[(q*4 + i)*AB_S + col] = f2bf(fmaxf(acc[i] + b, 0.f));
}

// posterior mid1 (in-loop): relu(h @ Wpo1h^T + po1_o[b0+r, t1]) (b_po1 folded)
// row-clamped for ROWS<16 padding.
__device__ __forceinline__ void stage256_add(
    const unsigned short* __restrict__ inA,
    const unsigned short* __restrict__ wt, int tbase,
    const unsigned short* __restrict__ Pbuf, int b0, int t1,
    unsigned short* __restrict__ outA, int lane, int wv)
{
  int q = lane >> 4, c16 = lane & 15;
  v8s wf[8];
  #pragma unroll
  for (int kt = 0; kt < 8; kt++) wf[kt] = LDB(tbase + wv*8 + kt);
  v8s af[8];
  #pragma unroll
  for (int kt = 0; kt < 8; kt++) af[kt] = *(const v8s*)&inA[c16*AB_S + kt*32 + q*8];
  int col = wv*16 + c16;
  unsigned short pv[4];
  #pragma unroll
  for (int i = 0; i < 4; i++){
    int r  = q*4 + i;
    int br = b0 + (r < ROWS ? r : ROWS-1);      // clamp padded rows
    pv[i] = __builtin_nontemporal_load(&Pbuf[((size_t)br*TN + t1)*256 + col]);
  }
  f32x4 acc = (f32x4){0.f,0.f,0.f,0.f};
  #pragma unroll
  for (int kt = 0; kt < 8; kt++) acc = MFMA16(af[kt], wf[kt], acc);
  #pragma unroll
  for (int i = 0; i < 4; i++){
    float v = acc[i] + bf2f(pv[i]);
    outA[(q*4 + i)*AB_S + col] = f2bf(fmaxf(v, 0.f));
  }
}

// heads (in-loop, overlay variant): 16 tasks = {mu/var} x {nt 0..7}; K = 256.
__device__ __forceinline__ void heads16(
    const unsigned short* __restrict__ AB2,
    const unsigned short* __restrict__ wt, int tM, int tV,
    const float* __restrict__ bM, const float* __restrict__ bV,
    float* __restrict__ muF, float* __restrict__ varF, int lane, int wv)
{
  int q = lane >> 4, c16 = lane & 15;
  int mtx = wv >> 3, nt = wv & 7;
  int tb  = mtx ? tV : tM;
  v8s wf[8];
  #pragma unroll
  for (int kt = 0; kt < 8; kt++) wf[kt] = LDB(tb + nt*8 + kt);
  v8s af[8];
  #pragma unroll
  for (int kt = 0; kt < 8; kt++) af[kt] = *(const v8s*)&AB2[c16*AB_S + kt*32 + q*8];
  __syncthreads();                 // everyone captured AB2 before overlay writes
  f32x4 acc = (f32x4){0.f,0.f,0.f,0.f};
  #pragma unroll
  for (int kt = 0; kt < 8; kt++) acc = MFMA16(af[kt], wf[kt], acc);
  int col = nt*16 + c16;
  float b = mtx ? bV[col] : bM[col];
  float* dst = mtx ? varF : muF;
  #pragma unroll
  for (int i = 0; i < 4; i++){
    float v = acc[i] + b;
    if (mtx) v = __expf(v) + 0.01f;
    dst[(q*4 + i)*LATN + col] = v;
  }
}

// heads (post-pass variant): dedicated dst arrays, no overlay, no sync.
__device__ __forceinline__ void pheads(
    const unsigned short* __restrict__ X2,
    const unsigned short* __restrict__ wt, int tM, int tV,
    const float* __restrict__ bM, const float* __restrict__ bV,
    float* __restrict__ muF, float* __restrict__ varF, int lane, int wv)
{
  int q = lane >> 4, c16 = lane & 15;
  int mtx = wv >> 3, nt = wv & 7;
  int tb  = mtx ? tV : tM;
  v8s wf[8];
  #pragma unroll
  for (int kt = 0; kt < 8; kt++) wf[kt] = LDB(tb + nt*8 + kt);
  v8s af[8];
  #pragma unroll
  for (int kt = 0; kt < 8; kt++) af[kt] = *(const v8s*)&X2[c16*AB_S + kt*32 + q*8];
  f32x4 acc = (f32x4){0.f,0.f,0.f,0.f};
  #pragma unroll
  for (int kt = 0; kt < 8; kt++) acc = MFMA16(af[kt], wf[kt], acc);
  int col = nt*16 + c16;
  float b = mtx ? bV[col] : bM[col];
  float* dst = mtx ? varF : muF;
  #pragma unroll
  for (int i = 0; i < 4; i++){
    float v = acc[i] + b;
    if (mtx) v = __expf(v) + 0.01f;
    dst[(q*4 + i)*LATN + col] = v;
  }
}

// posterior mid1 (post-pass): rows are flat (b*127+t); Pbuf row = grow+b+1.
__device__ __forceinline__ void pstage_add(
    const unsigned short* __restrict__ inA,
    const unsigned short* __restrict__ wt, int tbase,
    const unsigned short* __restrict__ Pbuf, int row0,
    unsigned short* __restrict__ outA, int lane, int wv)
{
  int q = lane >> 4, c16 = lane & 15;
  v8s wf[8];
  #pragma unroll
  for (int kt = 0; kt < 8; kt++) wf[kt] = LDB(tbase + wv*8 + kt);
  v8s af[8];
  #pragma unroll
  for (int kt = 0; kt < 8; kt++) af[kt] = *(const v8s*)&inA[c16*AB_S + kt*32 + q*8];
  int col = wv*16 + c16;
  unsigned short pv[4];
  #pragma unroll
  for (int i = 0; i < 4; i++){
    int grow = row0 + q*4 + i;          // = b*127 + t
    int prow = grow + grow/127 + 1;     // = b*128 + (t+1)
    pv[i] = __builtin_nontemporal_load(&Pbuf[(size_t)prow*256 + col]);
  }
  f32x4 acc = (f32x4){0.f,0.f,0.f,0.f};
  #pragma unroll
  for (int kt = 0; kt < 8; kt++) acc = MFMA16(af[kt], wf[kt], acc);
  #pragma unroll
  for (int i = 0; i < 4; i++){
    float v = acc[i] + bf2f(pv[i]);
    outA[(q*4 + i)*AB_S + col] = f2bf(fmaxf(v, 0.f));
  }
}

// ---------------------------------------------------------------------------
// Persistent recurrence: block g owns batch rows g*ROWS..g*ROWS+ROWS-1 for all
// steps. 1024 threads = 16 waves. Rows ROWS..15 of every 16-row tile are
// padding: MFMA rows are independent, so they carry garbage harmlessly;
// global loads are clamped, global stores predicated on r < ROWS.
// ---------------------------------------------------------------------------
__global__ __launch_bounds__(1024, 4) void rssm_rnn(
    const unsigned short* __restrict__ wt,
    const unsigned short* __restrict__ Pbuf,      // po1_o bf16 (B*T x 256)
    const float* __restrict__ actions, const float* __restrict__ noise,
    const float* __restrict__ w_gin,  const float* __restrict__ b_gin,
    const float* __restrict__ b_ih,   const float* __restrict__ b_hh,
    const float* __restrict__ b_po2,  const float* __restrict__ b_pom,
    const float* __restrict__ b_pov,
    unsigned short* __restrict__ Hb,              // h_t bf16 (B*127 x 256)
    float* __restrict__ out)
{
  __shared__ unsigned short sA [16*SA_S];
  __shared__ unsigned short hA [16*AB_S];
  __shared__ unsigned short AB1[16*AB_S];   // also overlaid as muq (f32 16x128)
  __shared__ unsigned short AB2[16*AB_S];   // also overlaid as varq
  __shared__ float hF   [16*256];
  __shared__ float aF   [16*8];

  float* muqF  = (float*)AB1;
  float* varqF = (float*)AB2;

  int tid = threadIdx.x, lane = tid & 63, wv = tid >> 6;
  int q = lane >> 4, c16 = lane & 15;
  int b0 = blockIdx.x * ROWS;

  for (int i = tid; i < 16*256; i += 1024) hF[i] = 0.f;
  for (int i = tid; i < 16*AB_S; i += 1024) hA[i] = 0;
  for (int i = tid; i < 16*SA_S; i += 1024) sA[i] = 0;

  // ---- s0: posterior with belief = 0 -> mid1 = relu(po1_o[:, t=0]) ----
  for (int i = tid; i < 16*256; i += 1024){
    int r = i >> 8, c = i & 255;
    int br = b0 + (r < ROWS ? r : ROWS-1);
    float v = bf2f(__builtin_nontemporal_load(&Pbuf[((size_t)br*TN + 0)*256 + c]));
    AB1[r*AB_S + c] = f2bf(fmaxf(v, 0.f));
  }
  __syncthreads();
  stage256(AB1, wt, PO2_T, b_po2, AB2, lane, wv);
  __syncthreads();
  heads16(AB2, wt, POM_T, POV_T, b_pom, b_pov, muqF, varqF, lane, wv);
  __syncthreads();
  if (wv < ROWS){
    int r = wv;
    #pragma unroll
    for (int ii = 0; ii < 2; ii++){
      int c = lane + ii*64;
      float mq = muqF[r*LATN + c], vq = varqF[r*LATN + c];
      float ep = __builtin_nontemporal_load(&noise[((size_t)0*BN + b0 + r)*LATN + c]);
      float sv = mq + sqrtf(vq)*ep;
      sA[r*SA_S + c] = f2bf(sv);
      __builtin_nontemporal_store(sv, &out[((size_t)(b0 + r)*TN + 0)*LATN + c]);
    }
  }
  __syncthreads();

  for (int t = 0; t < TN-1; t++){
    if (tid < 128){
      int rr = tid >> 3;
      int br = b0 + (rr < ROWS ? rr : ROWS-1);
      aF[tid] = __builtin_nontemporal_load(
          &actions[((size_t)br*127 + t)*8 + (tid & 7)]);
    }
    __syncthreads();

    // ---- g = relu(s @ WginS^T + a @ WginA^T + b_gin) -> AB1 ----
    {
      v8s wf[4];
      #pragma unroll
      for (int kt = 0; kt < 4; kt++) wf[kt] = LDB(GINS_T + wv*4 + kt);
      v8s af[4];
      #pragma unroll
      for (int kt = 0; kt < 4; kt++) af[kt] = *(const v8s*)&sA[c16*SA_S + kt*32 + q*8];
      int col = wv*16 + c16;
      float bg = b_gin[col];
      float wa[8];
      #pragma unroll
      for (int j = 0; j < 8; j++) wa[j] = w_gin[col*136 + 128 + j];
      f32x4 acc = (f32x4){0.f,0.f,0.f,0.f};
      #pragma unroll
      for (int kt = 0; kt < 4; kt++) acc = MFMA16(af[kt], wf[kt], acc);
      #pragma unroll
      for (int i = 0; i < 4; i++){
        int r = q*4 + i;
        float v = acc[i] + bg;
        #pragma unroll
        for (int j = 0; j < 8; j++) v += aF[r*8 + j]*wa[j];
        AB1[r*AB_S + col] = f2bf(fmaxf(v, 0.f));
      }
    }
    __syncthreads();

    // ---- GRU, two phases to bound VGPRs. Wave wv owns output cols
    //      wv*16..wv*16+15; gi strips nt = s*16+wv, gh strips likewise. ----
    float hnew[4];
    {
      int col = wv*16 + c16;
      // gi phase: g from AB1
      f32x4 accI[3];
      {
        v8s ag[8];
        #pragma unroll
        for (int kt = 0; kt < 8; kt++) ag[kt] = *(const v8s*)&AB1[c16*AB_S + kt*32 + q*8];
        #pragma unroll
        for (int s = 0; s < 3; s++){
          v8s wf[8];
          #pragma unroll
          for (int kt = 0; kt < 8; kt++) wf[kt] = LDB(IH_T + (s*16 + wv)*8 + kt);
          accI[s] = (f32x4){0.f,0.f,0.f,0.f};
          #pragma unroll
          for (int kt = 0; kt < 8; kt++) accI[s] = MFMA16(ag[kt], wf[kt], accI[s]);
        }
      }
      // gh phase: h from hA (old h); incremental gate evaluation
      float rg[4], zg[4];
      {
        v8s ah[8];
        #pragma unroll
        for (int kt = 0; kt < 8; kt++) ah[kt] = *(const v8s*)&hA[c16*AB_S + kt*32 + q*8];
        // r
        {
          v8s wf[8];
          #pragma unroll
          for (int kt = 0; kt < 8; kt++) wf[kt] = LDB(HH_T + (0*16 + wv)*8 + kt);
          f32x4 a = (f32x4){0.f,0.f,0.f,0.f};
          #pragma unroll
          for (int kt = 0; kt < 8; kt++) a = MFMA16(ah[kt], wf[kt], a);
          float bir = b_ih[col], bhr = b_hh[col];
          #pragma unroll
          for (int i = 0; i < 4; i++) rg[i] = sigm(accI[0][i] + bir + a[i] + bhr);
        }
        // z
        {
          v8s wf[8];
          #pragma unroll
          for (int kt = 0; kt < 8; kt++) wf[kt] = LDB(HH_T + (1*16 + wv)*8 + kt);
          f32x4 a = (f32x4){0.f,0.f,0.f,0.f};
          #pragma unroll
          for (int kt = 0; kt < 8; kt++) a = MFMA16(ah[kt], wf[kt], a);
          float biz = b_ih[256+col], bhz = b_hh[256+col];
          #pragma unroll
          for (int i = 0; i < 4; i++) zg[i] = sigm(accI[1][i] + biz + a[i] + bhz);
        }
        // n and h_new
        {
          v8s wf[8];
          #pragma unroll
          for (int kt = 0; kt < 8; kt++) wf[kt] = LDB(HH_T + (2*16 + wv)*8 + kt);
          f32x4 a = (f32x4){0.f,0.f,0.f,0.f};
          #pragma unroll
          for (int kt = 0; kt < 8; kt++) a = MFMA16(ah[kt], wf[kt], a);
          float bin = b_ih[512+col], bhn = b_hh[512+col];
          #pragma unroll
          for (int i = 0; i < 4; i++){
            int r = q*4 + i;
            float ng = tanhx(accI[2][i] + bin + rg[i]*(a[i] + bhn));
            float ho = hF[r*256 + col];
            float hv = (1.f - zg[i])*ng + zg[i]*ho;
            hF[r*256 + col] = hv;
            hnew[i] = hv;
          }
        }
      }
    }
    __syncthreads();   // all waves' ah reads done before hA is overwritten
    {
      int col = wv*16 + c16;
      #pragma unroll
      for (int i = 0; i < 4; i++){
        int r = q*4 + i;
        unsigned short hb = f2bf(hnew[i]);
        hA[r*AB_S + col] = hb;
        if (r < ROWS)
          __builtin_nontemporal_store(hb,
              &Hb[((size_t)(b0 + r)*127 + t)*256 + col]);
      }
    }
    __syncthreads();

    // ---- posterior (prior hoisted to post_pass) ----
    stage256_add(hA, wt, PO1H_T, Pbuf, b0, t+1, AB1, lane, wv);
    __syncthreads();
    stage256(AB1, wt, PO2_T, b_po2, AB2, lane, wv);
    __syncthreads();
    heads16(AB2, wt, POM_T, POV_T, b_pom, b_pov, muqF, varqF, lane, wv);
    __syncthreads();

    // ---- sample: wave wv owns batch row wv (only real rows) ----
    if (wv < ROWS){
      int r = wv;
      #pragma unroll
      for (int ii = 0; ii < 2; ii++){
        int c = lane + ii*64;
        float mq = muqF[r*LATN + c], vq = varqF[r*LATN + c];
        float ep = __builtin_nontemporal_load(
            &noise[((size_t)(t+1)*BN + b0 + r)*LATN + c]);
        float sv = mq + sqrtf(vq)*ep;
        sA[r*SA_S + c] = f2bf(sv);
        __builtin_nontemporal_store(sv, &out[((size_t)(b0 + r)*TN + (t+1))*LATN + c]);
      }
    }
    __syncthreads();
  }
}

// ---------------------------------------------------------------------------
// Parallel post-pass over all (b,t) rows: prior chain + posterior chain
// (bit-identical MFMA sequences to the in-loop versions) + KL.
// Block = 16 rows (flat row = b*127 + t), 16 waves.
// ---------------------------------------------------------------------------
__global__ __launch_bounds__(1024, 4) void post_pass(
    const unsigned short* __restrict__ wt,
    const unsigned short* __restrict__ Pbuf,
    const unsigned short* __restrict__ Hb,
    const float* __restrict__ b_pr1, const float* __restrict__ b_pr2,
    const float* __restrict__ b_prm, const float* __restrict__ b_prv,
    const float* __restrict__ b_po2, const float* __restrict__ b_pom,
    const float* __restrict__ b_pov,
    float* __restrict__ out)
{
  __shared__ unsigned short hC[16*AB_S];
  __shared__ unsigned short X1[16*AB_S];
  __shared__ unsigned short X2[16*AB_S];
  __shared__ float mupF[16*LATN], varpF[16*LATN];
  __shared__ float muqF[16*LATN], varqF[16*LATN];

  int tid = threadIdx.x, lane = tid & 63, wv = tid >> 6;
  int row0 = blockIdx.x * 16;

  if (tid < 512){
    int r = tid >> 5, c8 = (tid & 31)*8;
    *(v8s*)&hC[r*AB_S + c8] = *(const v8s*)&Hb[(size_t)(row0 + r)*256 + c8];
  }
  __syncthreads();

  // prior
  stage256(hC, wt, PR1_T, b_pr1, X1, lane, wv);
  __syncthreads();
  stage256(X1, wt, PR2_T, b_pr2, X2, lane, wv);
  __syncthreads();
  pheads(X2, wt, PRM_T, PRV_T, b_prm, b_prv, mupF, varpF, lane, wv);
  __syncthreads();

  // posterior (recompute; identical to in-loop)
  pstage_add(hC, wt, PO1H_T, Pbuf, row0, X1, lane, wv);
  __syncthreads();
  stage256(X1, wt, PO2_T, b_po2, X2, lane, wv);
  __syncthreads();
  pheads(X2, wt, POM_T, POV_T, b_pom, b_pov, muqF, varqF, lane, wv);
  __syncthreads();

  // KL: wave wv owns row wv
  {
    int r = wv;
    float kv = 0.f;
    #pragma unroll
    for (int ii = 0; ii < 2; ii++){
      int c = lane + ii*64;
      float mq = muqF[r*LATN + c], vq = varqF[r*LATN + c];
      float mp = mupF[r*LATN + c], vp = varpF[r*LATN + c];
      float d = mq - mp;
      kv += __logf(vp) - __logf(vq) + (vq + d*d)/vp - 1.f;
    }
    #pragma unroll
    for (int m = 1; m < 64; m <<= 1) kv += __shfl_xor(kv, m, 64);
    if (lane == 0)
      __builtin_nontemporal_store(0.5f*kv, &out[KL_OFF + (size_t)(row0 + r)]);
  }
}

// ---------------------------------------------------------------------------
extern "C" void kernel_launch(void* const* d_in, const int* in_sizes, int n_in,
                              void* d_out, int out_size, void* d_ws, size_t ws_size,
                              hipStream_t stream)
{
  (void)in_sizes; (void)n_in; (void)out_size; (void)ws_size;
  const float* vis    = (const float*)d_in[0];
  const float* acts   = (const float*)d_in[1];
  const float* noise  = (const float*)d_in[2];
  const float* w_obs1 = (const float*)d_in[3];
  const float* b_obs1 = (const float*)d_in[4];
  const float* w_obs2 = (const float*)d_in[5];
  const float* b_obs2 = (const float*)d_in[6];
  const float* w_gin  = (const float*)d_in[7];
  const float* b_gin  = (const float*)d_in[8];
  const float* w_ih   = (const float*)d_in[9];
  const float* w_hh   = (const float*)d_in[10];
  const float* b_ih   = (const float*)d_in[11];
  const float* b_hh   = (const float*)d_in[12];
  const float* w_pr1  = (const float*)d_in[13];
  const float* b_pr1  = (const float*)d_in[14];
  const float* w_pr2  = (const float*)d_in[15];
  const float* b_pr2  = (const float*)d_in[16];
  const float* w_prm  = (const float*)d_in[17];
  const float* b_prm  = (const float*)d_in[18];
  const float* w_prv  = (const float*)d_in[19];
  const float* b_prv  = (const float*)d_in[20];
  const float* w_po1  = (const float*)d_in[21];
  const float* b_po1  = (const float*)d_in[22];
  const float* w_po2  = (const float*)d_in[23];
  const float* b_po2  = (const float*)d_in[24];
  const float* w_pom  = (const float*)d_in[25];
  const float* b_pom  = (const float*)d_in[26];
  const float* w_pov  = (const float*)d_in[27];
  const float* b_pov  = (const float*)d_in[28];

  unsigned short* B1 = (unsigned short*)d_ws;                       // 65536x256 bf16
  unsigned short* WT = (unsigned short*)((char*)d_ws + B1_BYTES);   // shuffled tiles
  unsigned short* Hb = WT + (size_t)TOT_TILES*512;                  // h_t (B*127 x 256)

  ShufArgs sa;
  const float* srcs[14] = {w_obs1, w_obs2, w_po1, w_po1, w_gin, w_ih, w_hh,
                           w_pr1, w_pr2, w_prm, w_prv, w_po2, w_pom, w_pov};
  const int strides[14] = {512,256,512,512,136,256,256,256,256,256,256,256,256,256};
  const int coloffs[14] = {0,0,256,0,0,0,0,0,0,0,0,0,0,0};
  const int ktl[14]     = {16,8,8,8,4,8,8,8,8,8,8,8,8,8};
  const int tbas[14]    = {OBS1_T,OBS2_T,PO1O_T,PO1H_T,GINS_T,IH_T,HH_T,
                           PR1_T,PR2_T,PRM_T,PRV_T,PO2_T,POM_T,POV_T};
  const int tcnt[14]    = {256,128,128,128,64,384,384,128,128,64,64,128,64,64};
  for (int i = 0; i < 14; i++){
    sa.src[i] = srcs[i]; sa.stride[i] = strides[i]; sa.coloff[i] = coloffs[i];
    sa.ktiles[i] = ktl[i]; sa.tbase[i] = tbas[i]; sa.tcnt[i] = tcnt[i];
  }
  shuffle_w<<<TOT_TILES, 64, 0, stream>>>(sa, WT);

  // obs MLP + po1_o, all in-place in B1 (rows are block-exclusive)
  big_gemm<<<1024, 256, 0, stream>>>(vis, 1, 512, WT, OBS1_T, b_obs1, 1, B1);
  big_gemm<<<1024, 256, 0, stream>>>(B1,  0, 256, WT, OBS2_T, b_obs2, 1, B1);
  big_gemm<<<1024, 256, 0, stream>>>(B1,  0, 256, WT, PO1O_T, b_po1,  0, B1);

  rssm_rnn<<<NBLK, 1024, 0, stream>>>(WT, B1, acts, noise, w_gin, b_gin, b_ih, b_hh,
                                      b_po2, b_pom, b_pov, Hb, (float*)d_out);

  post_pass<<<4064, 1024, 0, stream>>>(WT, B1, Hb, b_pr1, b_pr2, b_prm, b_prv,
                                       b_po2, b_pom, b_pov, (float*)d_out);
}

// Round 3
// 4988.930 us; speedup vs baseline: 1.0507x; 1.0507x over previous
//
#include <hip/hip_runtime.h>
#include <math.h>

// ============================================================================
// RSSM forward on MI355X.
// Round 6: LDS-resident weights via 8-block column-split groups.
// R5 post-mortem: any design where one block computes all 256 cols must stream
// the 1.2MB/step serial weight set through its CU every step (one CU's
// VGPR+LDS = 672KB < 1.2MB) -> 32 blocks: 33.7us/step, 128 blocks: L2 thrash,
// 44.7us/step. Structural fix: 32 groups x 8 blocks (=256 CUs, 1/CU via LDS);
// block j of a group pins its 1/8 column-slice of every stage's weights in
// LDS (~139KB) ONCE, plus head weights in registers. Stages exchange 16x32
// activation slices through a small global buffer with device-scope
// atomic-epoch barriers (5 syncs/step; H double-buffered by step parity;
// monotonic targets, no counter reset). Group members at blockIdx = g + 32*j
// share blockIdx%8 -> same XCD under round-robin -> L2-local exchange.
// Tile order / bf16 rounding identical to R4 -> bit-identical results.
// ============================================================================

using v8s   = __attribute__((ext_vector_type(8))) short;
using f32x4 = __attribute__((ext_vector_type(4))) float;

#define BN   512
#define TN   128
#define LATN 128

#define AB_S 264   // 256-col LDS activation stride (shorts) - post_pass/big_gemm
#define SA_S 136

// pre-shuffled weight tile bases (1 tile = 16n x 32k bf16 = 1KB = 512 shorts)
#define OBS1_T 0
#define OBS2_T 256
#define PO1O_T 384
#define PO1H_T 512
#define GINS_T 640
#define IH_T   704
#define HH_T   1088
#define PR1_T  1472
#define PR2_T  1600
#define PRM_T  1728
#define PRV_T  1792
#define PO2_T  1856
#define POM_T  1984
#define POV_T  2048
#define TOT_TILES 2112

#define B1_BYTES 33554432UL          // 65536 x 256 bf16
#define KL_OFF   8388608UL           // states elements (512*128*128)

// local (LDS) tile bases for the rnn weight slices
#define GIN_L 0     // 8 tiles
#define IH_L  8     // 48
#define HH_L  56    // 48
#define P1_L  104   // 16
#define P2_L  120   // 16
#define NLT   136

__device__ __forceinline__ unsigned short f2bf(float f){
  union { float f; unsigned u; } v; v.f = f;
  unsigned u = v.u + 0x7fffu + ((v.u >> 16) & 1u);   // RNE
  return (unsigned short)(u >> 16);
}
__device__ __forceinline__ float bf2f(unsigned short s){
  union { unsigned u; float f; } v; v.u = ((unsigned)s) << 16; return v.f;
}
__device__ __forceinline__ float sigm(float x){ return 1.f / (1.f + __expf(-x)); }
__device__ __forceinline__ float tanhx(float x){ return 1.f - 2.f/(__expf(2.f*x) + 1.f); }

#define MFMA16(a,b,c) __builtin_amdgcn_mfma_f32_16x16x32_bf16((a),(b),(c),0,0,0)
#define LDB(tIdx) (*(const v8s*)(wt + ((size_t)(tIdx))*512 + lane*8))

// ---------------------------------------------------------------------------
// Weight shuffle: f32 (N,K) row-major -> bf16 fragment-linear tiles.
// ---------------------------------------------------------------------------
struct ShufArgs {
  const float* src[14];
  int stride[14], coloff[14], ktiles[14], tbase[14], tcnt[14];
};

__global__ __launch_bounds__(64) void shuffle_w(ShufArgs sa, unsigned short* __restrict__ wt)
{
  int tile = blockIdx.x;
  int s = 0;
  while (tile >= sa.tbase[s] + sa.tcnt[s]) s++;
  int lt = tile - sa.tbase[s];
  int kt = lt % sa.ktiles[s];
  int nt = lt / sa.ktiles[s];
  int l  = threadIdx.x;
  int n  = nt*16 + (l & 15);
  int k  = sa.coloff[s] + kt*32 + (l >> 4)*8;
  const float* sp = sa.src[s] + (size_t)n * sa.stride[s] + k;
  unsigned short* dp = wt + (size_t)tile*512 + (size_t)l*8;
  #pragma unroll
  for (int j = 0; j < 8; j++) dp[j] = f2bf(sp[j]);
}

// ---------------------------------------------------------------------------
// Parallel GEMM for obs MLP / po1_o precompute.
// ---------------------------------------------------------------------------
__global__ __launch_bounds__(256) void big_gemm(
    const void* __restrict__ Ain, int aIsF32, int K,
    const unsigned short* __restrict__ wt, int tbase,
    const float* __restrict__ bias, int doRelu,
    unsigned short* __restrict__ outB)
{
  __shared__ unsigned short AL[64*AB_S];
  int tid = threadIdx.x, lane = tid & 63, wv = tid >> 6;
  int q = lane >> 4, c16 = lane & 15;
  size_t row0 = (size_t)blockIdx.x * 64;

  f32x4 acc[16];
  #pragma unroll
  for (int nt = 0; nt < 16; nt++) acc[nt] = (f32x4){0.f,0.f,0.f,0.f};

  int nchunk = K >> 8;
  int ktT    = K >> 5;
  for (int cc = 0; cc < nchunk; cc++){
    int r = tid >> 2, c0 = (tid & 3) * 64;
    if (aIsF32){
      const float* A = (const float*)Ain + (row0 + r) * (size_t)K + (size_t)cc*256 + c0;
      #pragma unroll
      for (int ii = 0; ii < 16; ii++){
        float4 x = ((const float4*)A)[ii];
        ushort4 o;
        o.x = f2bf(x.x); o.y = f2bf(x.y); o.z = f2bf(x.z); o.w = f2bf(x.w);
        *(ushort4*)&AL[r*AB_S + c0 + ii*4] = o;
      }
    } else {
      const unsigned short* A = (const unsigned short*)Ain + (row0 + r)*256 + c0;
      #pragma unroll
      for (int ii = 0; ii < 8; ii++)
        *(v8s*)&AL[r*AB_S + c0 + ii*8] = *(const v8s*)(A + ii*8);
    }
    __syncthreads();
    const unsigned short* myA = &AL[wv*16*AB_S];
    #pragma unroll
    for (int kt = 0; kt < 8; kt++){
      v8s af = *(const v8s*)&myA[c16*AB_S + kt*32 + q*8];
      #pragma unroll
      for (int nt = 0; nt < 16; nt++){
        v8s bf = *(const v8s*)(wt + ((size_t)(tbase + nt*ktT + cc*8 + kt))*512 + lane*8);
        acc[nt] = MFMA16(af, bf, acc[nt]);
      }
    }
    __syncthreads();
  }
  #pragma unroll
  for (int nt = 0; nt < 16; nt++){
    int col = nt*16 + c16;
    float b = bias[col];
    #pragma unroll
    for (int i = 0; i < 4; i++){
      float v = acc[nt][i] + b;
      if (doRelu) v = fmaxf(v, 0.f);
      outB[(row0 + wv*16 + q*4 + i)*256 + col] = f2bf(v);
    }
  }
}

// ---------------------------------------------------------------------------
// post_pass helpers (16 rows x 256 cols, 16 waves; wave wv owns nt = wv).
// ---------------------------------------------------------------------------
__device__ __forceinline__ void stage256(
    const unsigned short* __restrict__ inA,
    const unsigned short* __restrict__ wt, int tbase,
    const float* __restrict__ bias,
    unsigned short* __restrict__ outA, int lane, int wv)
{
  int q = lane >> 4, c16 = lane & 15;
  v8s wf[8];
  #pragma unroll
  for (int kt = 0; kt < 8; kt++) wf[kt] = LDB(tbase + wv*8 + kt);
  v8s af[8];
  #pragma unroll
  for (int kt = 0; kt < 8; kt++) af[kt] = *(const v8s*)&inA[c16*AB_S + kt*32 + q*8];
  f32x4 acc = (f32x4){0.f,0.f,0.f,0.f};
  #pragma unroll
  for (int kt = 0; kt < 8; kt++) acc = MFMA16(af[kt], wf[kt], acc);
  int col = wv*16 + c16;
  float b = bias[col];
  #pragma unroll
  for (int i = 0; i < 4; i++)
    outA[(q*4 + i)*AB_S + col] = f2bf(fmaxf(acc[i] + b, 0.f));
}

__device__ __forceinline__ void pheads(
    const unsigned short* __restrict__ X2,
    const unsigned short* __restrict__ wt, int tM, int tV,
    const float* __restrict__ bM, const float* __restrict__ bV,
    float* __restrict__ muF, float* __restrict__ varF, int lane, int wv)
{
  int q = lane >> 4, c16 = lane & 15;
  int mtx = wv >> 3, nt = wv & 7;
  int tb  = mtx ? tV : tM;
  v8s wf[8];
  #pragma unroll
  for (int kt = 0; kt < 8; kt++) wf[kt] = LDB(tb + nt*8 + kt);
  v8s af[8];
  #pragma unroll
  for (int kt = 0; kt < 8; kt++) af[kt] = *(const v8s*)&X2[c16*AB_S + kt*32 + q*8];
  f32x4 acc = (f32x4){0.f,0.f,0.f,0.f};
  #pragma unroll
  for (int kt = 0; kt < 8; kt++) acc = MFMA16(af[kt], wf[kt], acc);
  int col = nt*16 + c16;
  float b = mtx ? bV[col] : bM[col];
  float* dst = mtx ? varF : muF;
  #pragma unroll
  for (int i = 0; i < 4; i++){
    float v = acc[i] + b;
    if (mtx) v = __expf(v) + 0.01f;
    dst[(q*4 + i)*LATN + col] = v;
  }
}

__device__ __forceinline__ void pstage_add(
    const unsigned short* __restrict__ inA,
    const unsigned short* __restrict__ wt, int tbase,
    const unsigned short* __restrict__ Pbuf, int row0,
    unsigned short* __restrict__ outA, int lane, int wv)
{
  int q = lane >> 4, c16 = lane & 15;
  v8s wf[8];
  #pragma unroll
  for (int kt = 0; kt < 8; kt++) wf[kt] = LDB(tbase + wv*8 + kt);
  v8s af[8];
  #pragma unroll
  for (int kt = 0; kt < 8; kt++) af[kt] = *(const v8s*)&inA[c16*AB_S + kt*32 + q*8];
  int col = wv*16 + c16;
  unsigned short pv[4];
  #pragma unroll
  for (int i = 0; i < 4; i++){
    int grow = row0 + q*4 + i;          // = b*127 + t
    int prow = grow + grow/127 + 1;     // = b*128 + (t+1)
    pv[i] = __builtin_nontemporal_load(&Pbuf[(size_t)prow*256 + col]);
  }
  f32x4 acc = (f32x4){0.f,0.f,0.f,0.f};
  #pragma unroll
  for (int kt = 0; kt < 8; kt++) acc = MFMA16(af[kt], wf[kt], acc);
  #pragma unroll
  for (int i = 0; i < 4; i++){
    float v = acc[i] + bf2f(pv[i]);
    outA[(q*4 + i)*AB_S + col] = f2bf(fmaxf(v, 0.f));
  }
}

// ---------------------------------------------------------------------------
// Group barrier: monotonic epoch counters, device scope.
// __syncthreads drains this block's stores (vmcnt0 before s_barrier); tid0's
// release-add flushes L2 for cross-XCD visibility; acquire-load invalidates
// stale lines before the post-barrier slice reads.
// ---------------------------------------------------------------------------
__device__ __forceinline__ void gsync(unsigned* c, unsigned tgt, int tid)
{
  __syncthreads();
  if (tid == 0){
    __hip_atomic_fetch_add(c, 1u, __ATOMIC_RELEASE, __HIP_MEMORY_SCOPE_AGENT);
    while (__hip_atomic_load(c, __ATOMIC_RELAXED, __HIP_MEMORY_SCOPE_AGENT) < tgt)
      __builtin_amdgcn_s_sleep(2);
    (void)__hip_atomic_load(c, __ATOMIC_ACQUIRE, __HIP_MEMORY_SCOPE_AGENT);
  }
  __syncthreads();
}

// ---------------------------------------------------------------------------
// Distributed recurrence. Grid 256 = 32 groups x 8 members; group g handles
// batch rows g*16..g*16+15; member j owns output cols [32j,32j+32) of every
// 256-wide stage and latent cols [16j,16j+16) of the heads. 128 threads =
// 2 waves; wave wv owns ntile 2j+wv (cols 32j+16wv+..).
// ---------------------------------------------------------------------------
struct RnnArgs {
  const unsigned short *wt, *Pbuf;
  const float *actions, *noise, *w_gin, *b_gin, *b_ih, *b_hh, *b_po2, *b_pom, *b_pov;
  unsigned short *Hb, *XS, *XG, *XH, *XM1, *XM2;
  unsigned *cnt;
  float *out;
};

__global__ __launch_bounds__(128, 1) void rssm_rnn(RnnArgs A)
{
  __shared__ unsigned short Lw[NLT*512];     // 139264 B weight slices
  __shared__ float LwaA[256];                // w_gin action part [32 cols][8]
  __shared__ float Lbg[32], Lbih[96], Lbhh[96], Lbp2[32], Lbm[16], Lbv[16];
  __shared__ float muv[2][16][16];
  __shared__ float aF[128];

  int tid = threadIdx.x, lane = tid & 63, wv = tid >> 6;
  int q = lane >> 4, c16 = lane & 15;
  int g = blockIdx.x & 31, j = blockIdx.x >> 5;   // members j share blockIdx%8 -> same XCD
  int b0 = g * 16;
  int lc = wv*16 + c16;          // local col in the 32-wide slice
  int gc = 32*j + lc;            // global col

  // ---- pin weight slices in LDS ----
  for (int u = tid; u < NLT*64; u += 128){
    int lt = u >> 6, ch = u & 63;
    int gt;
    if (lt < 8){
      int w = lt >> 2, kt = lt & 3;
      gt = GINS_T + (2*j + w)*4 + kt;
    } else if (lt < 56){
      int u2 = lt - 8;
      gt = IH_T + ((u2 >> 4)*16 + 2*j + ((u2 >> 3) & 1))*8 + (u2 & 7);
    } else if (lt < 104){
      int u2 = lt - 56;
      gt = HH_T + ((u2 >> 4)*16 + 2*j + ((u2 >> 3) & 1))*8 + (u2 & 7);
    } else if (lt < 120){
      int u2 = lt - 104;
      gt = PO1H_T + (2*j + (u2 >> 3))*8 + (u2 & 7);
    } else {
      int u2 = lt - 120;
      gt = PO2_T + (2*j + (u2 >> 3))*8 + (u2 & 7);
    }
    *(v8s*)&Lw[lt*512 + ch*8] = *(const v8s*)(A.wt + (size_t)gt*512 + ch*8);
  }
  for (int u = tid; u < 256; u += 128)
    LwaA[u] = A.w_gin[(size_t)(32*j + (u >> 3))*136 + 128 + (u & 7)];
  if (tid < 32){ Lbg[tid] = A.b_gin[32*j + tid]; Lbp2[tid] = A.b_po2[32*j + tid]; }
  if (tid >= 32 && tid < 128){
    int u = tid - 32;
    if (u < 96){
      Lbih[u] = A.b_ih[(u >> 5)*256 + 32*j + (u & 31)];
      Lbhh[u] = A.b_hh[(u >> 5)*256 + 32*j + (u & 31)];
    }
  }
  if (tid < 16){ Lbm[tid] = A.b_pom[16*j + tid]; Lbv[tid] = A.b_pov[16*j + tid]; }

  v8s wh[8];   // head weights persistent in registers (wave0: pom, wave1: pov)
  {
    const unsigned short* wt = A.wt;
    int tb = (wv ? POV_T : POM_T) + j*8;
    #pragma unroll
    for (int kt = 0; kt < 8; kt++) wh[kt] = LDB(tb + kt);
  }
  float hFr[4] = {0.f, 0.f, 0.f, 0.f};   // f32 h carry, rows q*4+i, col gc
  __syncthreads();

  unsigned* cS  = A.cnt + g*16 + 0;
  unsigned* cG  = A.cnt + g*16 + 1;
  unsigned* cH  = A.cnt + g*16 + 2;
  unsigned* cM1 = A.cnt + g*16 + 3;
  unsigned* cM2 = A.cnt + g*16 + 4;
  const size_t sl = (size_t)(g*8);   // slice index base for this group

  for (int t = -1; t < TN-1; t++){
    unsigned e2 = (unsigned)(8*(t+2));
    if (t >= 0){
      aF[tid] = __builtin_nontemporal_load(
          &A.actions[((size_t)(b0 + (tid >> 3))*127 + t)*8 + (tid & 7)]);
      __syncthreads();
      // ---- gin: g = relu(s @ WginS^T + a @ WginA^T + b_gin) ----
      {
        v8s af4[4], wf[4];
        #pragma unroll
        for (int kt = 0; kt < 4; kt++)
          af4[kt] = *(const v8s*)(A.XS + ((sl + 2*kt + (q >> 1))*16 + c16)*16 + (q & 1)*8);
        #pragma unroll
        for (int kt = 0; kt < 4; kt++)
          wf[kt] = *(const v8s*)&Lw[(GIN_L + wv*4 + kt)*512 + lane*8];
        f32x4 acc = (f32x4){0.f,0.f,0.f,0.f};
        #pragma unroll
        for (int kt = 0; kt < 4; kt++) acc = MFMA16(af4[kt], wf[kt], acc);
        float bg = Lbg[lc];
        #pragma unroll
        for (int i = 0; i < 4; i++){
          int r = q*4 + i;
          float v = acc[i] + bg;
          #pragma unroll
          for (int m = 0; m < 8; m++) v += aF[r*8 + m]*LwaA[lc*8 + m];
          A.XG[((sl + j)*16 + r)*32 + lc] = f2bf(fmaxf(v, 0.f));
        }
      }
      gsync(cG, (unsigned)(8*(t+1)), tid);
      // ---- GRU ----
      {
        int p = t & 1;
        v8s ag[8], ah[8];
        #pragma unroll
        for (int kt = 0; kt < 8; kt++){
          ag[kt] = *(const v8s*)(A.XG + ((sl + kt)*16 + c16)*32 + q*8);
          ah[kt] = *(const v8s*)(A.XH + (((size_t)p*256 + sl + kt)*16 + c16)*32 + q*8);
        }
        f32x4 accI[3];
        #pragma unroll
        for (int x = 0; x < 3; x++){
          v8s wf[8];
          #pragma unroll
          for (int kt = 0; kt < 8; kt++)
            wf[kt] = *(const v8s*)&Lw[(IH_L + (x*2 + wv)*8 + kt)*512 + lane*8];
          accI[x] = (f32x4){0.f,0.f,0.f,0.f};
          #pragma unroll
          for (int kt = 0; kt < 8; kt++) accI[x] = MFMA16(ag[kt], wf[kt], accI[x]);
        }
        float rg[4], zg[4];
        {
          v8s wf[8];
          #pragma unroll
          for (int kt = 0; kt < 8; kt++)
            wf[kt] = *(const v8s*)&Lw[(HH_L + (0*2 + wv)*8 + kt)*512 + lane*8];
          f32x4 a = (f32x4){0.f,0.f,0.f,0.f};
          #pragma unroll
          for (int kt = 0; kt < 8; kt++) a = MFMA16(ah[kt], wf[kt], a);
          float bir = Lbih[lc], bhr = Lbhh[lc];
          #pragma unroll
          for (int i = 0; i < 4; i++) rg[i] = sigm(accI[0][i] + bir + a[i] + bhr);
        }
        {
          v8s wf[8];
          #pragma unroll
          for (int kt = 0; kt < 8; kt++)
            wf[kt] = *(const v8s*)&Lw[(HH_L + (1*2 + wv)*8 + kt)*512 + lane*8];
          f32x4 a = (f32x4){0.f,0.f,0.f,0.f};
          #pragma unroll
          for (int kt = 0; kt < 8; kt++) a = MFMA16(ah[kt], wf[kt], a);
          float biz = Lbih[32 + lc], bhz = Lbhh[32 + lc];
          #pragma unroll
          for (int i = 0; i < 4; i++) zg[i] = sigm(accI[1][i] + biz + a[i] + bhz);
        }
        {
          v8s wf[8];
          #pragma unroll
          for (int kt = 0; kt < 8; kt++)
            wf[kt] = *(const v8s*)&Lw[(HH_L + (2*2 + wv)*8 + kt)*512 + lane*8];
          f32x4 a = (f32x4){0.f,0.f,0.f,0.f};
          #pragma unroll
          for (int kt = 0; kt < 8; kt++) a = MFMA16(ah[kt], wf[kt], a);
          float bin = Lbih[64 + lc], bhn = Lbhh[64 + lc];
          #pragma unroll
          for (int i = 0; i < 4; i++){
            int r = q*4 + i;
            float ng = tanhx(accI[2][i] + bin + rg[i]*(a[i] + bhn));
            float hv = (1.f - zg[i])*ng + zg[i]*hFr[i];
            hFr[i] = hv;
            unsigned short hb = f2bf(hv);
            A.XH[(((size_t)(1 - p)*256 + sl + j)*16 + r)*32 + lc] = hb;
            __builtin_nontemporal_store(hb, &A.Hb[((size_t)(b0 + r)*127 + t)*256 + gc]);
          }
        }
      }
      gsync(cH, (unsigned)(8*(t+1)), tid);
      // ---- po1h -> m1 ----
      {
        int p = t & 1;
        v8s ah[8], wf[8];
        #pragma unroll
        for (int kt = 0; kt < 8; kt++)
          ah[kt] = *(const v8s*)(A.XH + (((size_t)(1 - p)*256 + sl + kt)*16 + c16)*32 + q*8);
        #pragma unroll
        for (int kt = 0; kt < 8; kt++)
          wf[kt] = *(const v8s*)&Lw[(P1_L + wv*8 + kt)*512 + lane*8];
        unsigned short pv[4];
        #pragma unroll
        for (int i = 0; i < 4; i++)
          pv[i] = __builtin_nontemporal_load(
              &A.Pbuf[((size_t)(b0 + q*4 + i)*TN + (t+1))*256 + gc]);
        f32x4 acc = (f32x4){0.f,0.f,0.f,0.f};
        #pragma unroll
        for (int kt = 0; kt < 8; kt++) acc = MFMA16(ah[kt], wf[kt], acc);
        #pragma unroll
        for (int i = 0; i < 4; i++)
          A.XM1[((sl + j)*16 + q*4 + i)*32 + lc] = f2bf(fmaxf(acc[i] + bf2f(pv[i]), 0.f));
      }
    } else {
      // ---- prologue: m1 = relu(po1_o[:, t=0]) (belief = 0) ----
      #pragma unroll
      for (int i = 0; i < 4; i++){
        int r = q*4 + i;
        unsigned short pv = __builtin_nontemporal_load(
            &A.Pbuf[((size_t)(b0 + r)*TN + 0)*256 + gc]);
        A.XM1[((sl + j)*16 + r)*32 + lc] = f2bf(fmaxf(bf2f(pv), 0.f));
      }
    }
    gsync(cM1, e2, tid);
    // ---- po2 -> m2 ----
    {
      v8s am[8], wf[8];
      #pragma unroll
      for (int kt = 0; kt < 8; kt++)
        am[kt] = *(const v8s*)(A.XM1 + ((sl + kt)*16 + c16)*32 + q*8);
      #pragma unroll
      for (int kt = 0; kt < 8; kt++)
        wf[kt] = *(const v8s*)&Lw[(P2_L + wv*8 + kt)*512 + lane*8];
      f32x4 acc = (f32x4){0.f,0.f,0.f,0.f};
      #pragma unroll
      for (int kt = 0; kt < 8; kt++) acc = MFMA16(am[kt], wf[kt], acc);
      #pragma unroll
      for (int i = 0; i < 4; i++)
        A.XM2[((sl + j)*16 + q*4 + i)*32 + lc] = f2bf(fmaxf(acc[i] + Lbp2[lc], 0.f));
    }
    gsync(cM2, e2, tid);
    // ---- heads (wave0: mu, wave1: var) ----
    {
      v8s am[8];
      #pragma unroll
      for (int kt = 0; kt < 8; kt++)
        am[kt] = *(const v8s*)(A.XM2 + ((sl + kt)*16 + c16)*32 + q*8);
      f32x4 acc = (f32x4){0.f,0.f,0.f,0.f};
      #pragma unroll
      for (int kt = 0; kt < 8; kt++) acc = MFMA16(am[kt], wh[kt], acc);
      #pragma unroll
      for (int i = 0; i < 4; i++){
        float v = acc[i] + (wv ? Lbv[c16] : Lbm[c16]);
        if (wv) v = __expf(v) + 0.01f;
        muv[wv][q*4 + i][c16] = v;
      }
    }
    __syncthreads();
    // ---- sample: s = mu + sqrt(var)*eps ----
    for (int u = tid; u < 256; u += 128){
      int r = u >> 4, c = u & 15;
      float mq = muv[0][r][c], vq = muv[1][r][c];
      float ep = __builtin_nontemporal_load(
          &A.noise[((size_t)(t+1)*BN + b0 + r)*LATN + 16*j + c]);
      float sv = mq + sqrtf(vq)*ep;
      __builtin_nontemporal_store(sv, &A.out[((size_t)(b0 + r)*TN + (t+1))*LATN + 16*j + c]);
      A.XS[(sl + j)*256 + r*16 + c] = f2bf(sv);
    }
    gsync(cS, e2, tid);
  }
}

// ---------------------------------------------------------------------------
// Parallel post-pass over all (b,t) rows: prior + posterior + KL.
// ---------------------------------------------------------------------------
__global__ __launch_bounds__(1024, 4) void post_pass(
    const unsigned short* __restrict__ wt,
    const unsigned short* __restrict__ Pbuf,
    const unsigned short* __restrict__ Hb,
    const float* __restrict__ b_pr1, const float* __restrict__ b_pr2,
    const float* __restrict__ b_prm, const float* __restrict__ b_prv,
    const float* __restrict__ b_po2, const float* __restrict__ b_pom,
    const float* __restrict__ b_pov,
    float* __restrict__ out)
{
  __shared__ unsigned short hC[16*AB_S];
  __shared__ unsigned short X1[16*AB_S];
  __shared__ unsigned short X2[16*AB_S];
  __shared__ float mupF[16*LATN], varpF[16*LATN];
  __shared__ float muqF[16*LATN], varqF[16*LATN];

  int tid = threadIdx.x, lane = tid & 63, wv = tid >> 6;
  int row0 = blockIdx.x * 16;

  if (tid < 512){
    int r = tid >> 5, c8 = (tid & 31)*8;
    *(v8s*)&hC[r*AB_S + c8] = *(const v8s*)&Hb[(size_t)(row0 + r)*256 + c8];
  }
  __syncthreads();

  stage256(hC, wt, PR1_T, b_pr1, X1, lane, wv);
  __syncthreads();
  stage256(X1, wt, PR2_T, b_pr2, X2, lane, wv);
  __syncthreads();
  pheads(X2, wt, PRM_T, PRV_T, b_prm, b_prv, mupF, varpF, lane, wv);
  __syncthreads();

  pstage_add(hC, wt, PO1H_T, Pbuf, row0, X1, lane, wv);
  __syncthreads();
  stage256(X1, wt, PO2_T, b_po2, X2, lane, wv);
  __syncthreads();
  pheads(X2, wt, POM_T, POV_T, b_pom, b_pov, muqF, varqF, lane, wv);
  __syncthreads();

  {
    int r = wv;
    float kv = 0.f;
    #pragma unroll
    for (int ii = 0; ii < 2; ii++){
      int c = lane + ii*64;
      float mq = muqF[r*LATN + c], vq = varqF[r*LATN + c];
      float mp = mupF[r*LATN + c], vp = varpF[r*LATN + c];
      float d = mq - mp;
      kv += __logf(vp) - __logf(vq) + (vq + d*d)/vp - 1.f;
    }
    #pragma unroll
    for (int m = 1; m < 64; m <<= 1) kv += __shfl_xor(kv, m, 64);
    if (lane == 0)
      __builtin_nontemporal_store(0.5f*kv, &out[KL_OFF + (size_t)(row0 + r)]);
  }
}

// ---------------------------------------------------------------------------
extern "C" void kernel_launch(void* const* d_in, const int* in_sizes, int n_in,
                              void* d_out, int out_size, void* d_ws, size_t ws_size,
                              hipStream_t stream)
{
  (void)in_sizes; (void)n_in; (void)out_size; (void)ws_size;
  const float* vis    = (const float*)d_in[0];
  const float* acts   = (const float*)d_in[1];
  const float* noise  = (const float*)d_in[2];
  const float* w_obs1 = (const float*)d_in[3];
  const float* b_obs1 = (const float*)d_in[4];
  const float* w_obs2 = (const float*)d_in[5];
  const float* b_obs2 = (const float*)d_in[6];
  const float* w_gin  = (const float*)d_in[7];
  const float* b_gin  = (const float*)d_in[8];
  const float* w_ih   = (const float*)d_in[9];
  const float* w_hh   = (const float*)d_in[10];
  const float* b_ih   = (const float*)d_in[11];
  const float* b_hh   = (const float*)d_in[12];
  const float* w_pr1  = (const float*)d_in[13];
  const float* b_pr1  = (const float*)d_in[14];
  const float* w_pr2  = (const float*)d_in[15];
  const float* b_pr2  = (const float*)d_in[16];
  const float* w_prm  = (const float*)d_in[17];
  const float* b_prm  = (const float*)d_in[18];
  const float* w_prv  = (const float*)d_in[19];
  const float* b_prv  = (const float*)d_in[20];
  const float* w_po1  = (const float*)d_in[21];
  const float* b_po1  = (const float*)d_in[22];
  const float* w_po2  = (const float*)d_in[23];
  const float* b_po2  = (const float*)d_in[24];
  const float* w_pom  = (const float*)d_in[25];
  const float* b_pom  = (const float*)d_in[26];
  const float* w_pov  = (const float*)d_in[27];
  const float* b_pov  = (const float*)d_in[28];

  unsigned short* B1 = (unsigned short*)d_ws;                       // 65536x256 bf16
  unsigned short* WT = (unsigned short*)((char*)d_ws + B1_BYTES);   // shuffled tiles
  unsigned short* Hb  = WT + (size_t)TOT_TILES*512;                 // h_t (B*127 x 256)
  unsigned short* XS  = Hb + (size_t)BN*127*256;                    // s slices
  unsigned short* XG  = XS + 32*8*256;
  unsigned short* XH  = XG + 32*8*512;
  unsigned short* XM1 = XH + (size_t)2*32*8*512;
  unsigned short* XM2 = XM1 + 32*8*512;
  unsigned*       CNT = (unsigned*)(XM2 + 32*8*512);

  ShufArgs sa;
  const float* srcs[14] = {w_obs1, w_obs2, w_po1, w_po1, w_gin, w_ih, w_hh,
                           w_pr1, w_pr2, w_prm, w_prv, w_po2, w_pom, w_pov};
  const int strides[14] = {512,256,512,512,136,256,256,256,256,256,256,256,256,256};
  const int coloffs[14] = {0,0,256,0,0,0,0,0,0,0,0,0,0,0};
  const int ktl[14]     = {16,8,8,8,4,8,8,8,8,8,8,8,8,8};
  const int tbas[14]    = {OBS1_T,OBS2_T,PO1O_T,PO1H_T,GINS_T,IH_T,HH_T,
                           PR1_T,PR2_T,PRM_T,PRV_T,PO2_T,POM_T,POV_T};
  const int tcnt[14]    = {256,128,128,128,64,384,384,128,128,64,64,128,64,64};
  for (int i = 0; i < 14; i++){
    sa.src[i] = srcs[i]; sa.stride[i] = strides[i]; sa.coloff[i] = coloffs[i];
    sa.ktiles[i] = ktl[i]; sa.tbase[i] = tbas[i]; sa.tcnt[i] = tcnt[i];
  }
  shuffle_w<<<TOT_TILES, 64, 0, stream>>>(sa, WT);

  // obs MLP + po1_o, all in-place in B1 (rows are block-exclusive)
  big_gemm<<<1024, 256, 0, stream>>>(vis, 1, 512, WT, OBS1_T, b_obs1, 1, B1);
  big_gemm<<<1024, 256, 0, stream>>>(B1,  0, 256, WT, OBS2_T, b_obs2, 1, B1);
  big_gemm<<<1024, 256, 0, stream>>>(B1,  0, 256, WT, PO1O_T, b_po1,  0, B1);

  // zero H parity buffers + barrier counters (replayed each graph run)
  hipMemsetAsync(XH, 0, (size_t)2*32*8*512*2, stream);
  hipMemsetAsync(CNT, 0, 32*16*4, stream);

  RnnArgs ra;
  ra.wt = WT; ra.Pbuf = B1;
  ra.actions = acts; ra.noise = noise; ra.w_gin = w_gin;
  ra.b_gin = b_gin; ra.b_ih = b_ih; ra.b_hh = b_hh;
  ra.b_po2 = b_po2; ra.b_pom = b_pom; ra.b_pov = b_pov;
  ra.Hb = Hb; ra.XS = XS; ra.XG = XG; ra.XH = XH; ra.XM1 = XM1; ra.XM2 = XM2;
  ra.cnt = CNT; ra.out = (float*)d_out;
  rssm_rnn<<<256, 128, 0, stream>>>(ra);

  post_pass<<<4064, 1024, 0, stream>>>(WT, B1, Hb, b_pr1, b_pr2, b_prm, b_prv,
                                       b_po2, b_pom, b_pov, (float*)d_out);
}

// Round 4
// 2063.902 us; speedup vs baseline: 2.5398x; 2.4172x over previous
//
#include <hip/hip_runtime.h>
#include <math.h>

// ============================================================================
// RSSM forward on MI355X.
// Round 7: cheap group barriers. R6 post-mortem: weights are LDS-resident
// (FETCH 8.4e6 -> 44.5e3 KB) but dur unchanged -> the 5 gsyncs/step cost
// ~6.9us each. Cause: agent-scope release/acquire on gfx950 emit buffer_wbl2 /
// buffer_inv (full per-XCD L2 writeback+invalidate, WRITE_SIZE 220MB vs 67MB
// useful). Fix: hand-built protocol -- exchange data moves via write-through
// device-coherent stores/loads (__hip_atomic_* relaxed AGENT scope; complete
// at the IF coherence point, no L2 maintenance), __syncthreads' vmcnt(0)
// drain makes stores visible before the flag, and the barrier counter is a
// relaxed agent fetch_add + relaxed spin. Correct under any workgroup->XCD
// placement. Epochs / H parity / tile order / rounding identical to R6.
// ============================================================================

using v8s   = __attribute__((ext_vector_type(8))) short;
using f32x4 = __attribute__((ext_vector_type(4))) float;
typedef unsigned long long u64;

#define BN   512
#define TN   128
#define LATN 128

#define AB_S 264   // 256-col LDS activation stride (shorts) - post_pass/big_gemm
#define SA_S 136

// pre-shuffled weight tile bases (1 tile = 16n x 32k bf16 = 1KB = 512 shorts)
#define OBS1_T 0
#define OBS2_T 256
#define PO1O_T 384
#define PO1H_T 512
#define GINS_T 640
#define IH_T   704
#define HH_T   1088
#define PR1_T  1472
#define PR2_T  1600
#define PRM_T  1728
#define PRV_T  1792
#define PO2_T  1856
#define POM_T  1984
#define POV_T  2048
#define TOT_TILES 2112

#define B1_BYTES 33554432UL          // 65536 x 256 bf16
#define KL_OFF   8388608UL           // states elements (512*128*128)

// local (LDS) tile bases for the rnn weight slices
#define GIN_L 0     // 8 tiles
#define IH_L  8     // 48
#define HH_L  56    // 48
#define P1_L  104   // 16
#define P2_L  120   // 16
#define NLT   136

__device__ __forceinline__ unsigned short f2bf(float f){
  union { float f; unsigned u; } v; v.f = f;
  unsigned u = v.u + 0x7fffu + ((v.u >> 16) & 1u);   // RNE
  return (unsigned short)(u >> 16);
}
__device__ __forceinline__ float bf2f(unsigned short s){
  union { unsigned u; float f; } v; v.u = ((unsigned)s) << 16; return v.f;
}
__device__ __forceinline__ float sigm(float x){ return 1.f / (1.f + __expf(-x)); }
__device__ __forceinline__ float tanhx(float x){ return 1.f - 2.f/(__expf(2.f*x) + 1.f); }

#define MFMA16(a,b,c) __builtin_amdgcn_mfma_f32_16x16x32_bf16((a),(b),(c),0,0,0)
#define LDB(tIdx) (*(const v8s*)(wt + ((size_t)(tIdx))*512 + lane*8))

// device-coherent exchange primitives (bypass non-coherent L1/L2; complete at
// the coherence point; no wbl2/inv cache maintenance)
__device__ __forceinline__ void stx16(unsigned short* p, v8s v){
  union { u64 u[2]; v8s v; } x; x.v = v;
  __hip_atomic_store((u64*)p,     x.u[0], __ATOMIC_RELAXED, __HIP_MEMORY_SCOPE_AGENT);
  __hip_atomic_store((u64*)p + 1, x.u[1], __ATOMIC_RELAXED, __HIP_MEMORY_SCOPE_AGENT);
}
__device__ __forceinline__ v8s ldx16(const unsigned short* p){
  union { u64 u[2]; v8s v; } x;
  x.u[0] = __hip_atomic_load((u64*)p,     __ATOMIC_RELAXED, __HIP_MEMORY_SCOPE_AGENT);
  x.u[1] = __hip_atomic_load((u64*)p + 1, __ATOMIC_RELAXED, __HIP_MEMORY_SCOPE_AGENT);
  return x.v;
}
__device__ __forceinline__ void stxs(unsigned short* p, unsigned short v){
  __hip_atomic_store(p, v, __ATOMIC_RELAXED, __HIP_MEMORY_SCOPE_AGENT);
}

// ---------------------------------------------------------------------------
// Weight shuffle: f32 (N,K) row-major -> bf16 fragment-linear tiles.
// ---------------------------------------------------------------------------
struct ShufArgs {
  const float* src[14];
  int stride[14], coloff[14], ktiles[14], tbase[14], tcnt[14];
};

__global__ __launch_bounds__(64) void shuffle_w(ShufArgs sa, unsigned short* __restrict__ wt)
{
  int tile = blockIdx.x;
  int s = 0;
  while (tile >= sa.tbase[s] + sa.tcnt[s]) s++;
  int lt = tile - sa.tbase[s];
  int kt = lt % sa.ktiles[s];
  int nt = lt / sa.ktiles[s];
  int l  = threadIdx.x;
  int n  = nt*16 + (l & 15);
  int k  = sa.coloff[s] + kt*32 + (l >> 4)*8;
  const float* sp = sa.src[s] + (size_t)n * sa.stride[s] + k;
  unsigned short* dp = wt + (size_t)tile*512 + (size_t)l*8;
  #pragma unroll
  for (int j = 0; j < 8; j++) dp[j] = f2bf(sp[j]);
}

// ---------------------------------------------------------------------------
// Parallel GEMM for obs MLP / po1_o precompute.
// ---------------------------------------------------------------------------
__global__ __launch_bounds__(256) void big_gemm(
    const void* __restrict__ Ain, int aIsF32, int K,
    const unsigned short* __restrict__ wt, int tbase,
    const float* __restrict__ bias, int doRelu,
    unsigned short* __restrict__ outB)
{
  __shared__ unsigned short AL[64*AB_S];
  int tid = threadIdx.x, lane = tid & 63, wv = tid >> 6;
  int q = lane >> 4, c16 = lane & 15;
  size_t row0 = (size_t)blockIdx.x * 64;

  f32x4 acc[16];
  #pragma unroll
  for (int nt = 0; nt < 16; nt++) acc[nt] = (f32x4){0.f,0.f,0.f,0.f};

  int nchunk = K >> 8;
  int ktT    = K >> 5;
  for (int cc = 0; cc < nchunk; cc++){
    int r = tid >> 2, c0 = (tid & 3) * 64;
    if (aIsF32){
      const float* A = (const float*)Ain + (row0 + r) * (size_t)K + (size_t)cc*256 + c0;
      #pragma unroll
      for (int ii = 0; ii < 16; ii++){
        float4 x = ((const float4*)A)[ii];
        ushort4 o;
        o.x = f2bf(x.x); o.y = f2bf(x.y); o.z = f2bf(x.z); o.w = f2bf(x.w);
        *(ushort4*)&AL[r*AB_S + c0 + ii*4] = o;
      }
    } else {
      const unsigned short* A = (const unsigned short*)Ain + (row0 + r)*256 + c0;
      #pragma unroll
      for (int ii = 0; ii < 8; ii++)
        *(v8s*)&AL[r*AB_S + c0 + ii*8] = *(const v8s*)(A + ii*8);
    }
    __syncthreads();
    const unsigned short* myA = &AL[wv*16*AB_S];
    #pragma unroll
    for (int kt = 0; kt < 8; kt++){
      v8s af = *(const v8s*)&myA[c16*AB_S + kt*32 + q*8];
      #pragma unroll
      for (int nt = 0; nt < 16; nt++){
        v8s bf = *(const v8s*)(wt + ((size_t)(tbase + nt*ktT + cc*8 + kt))*512 + lane*8);
        acc[nt] = MFMA16(af, bf, acc[nt]);
      }
    }
    __syncthreads();
  }
  #pragma unroll
  for (int nt = 0; nt < 16; nt++){
    int col = nt*16 + c16;
    float b = bias[col];
    #pragma unroll
    for (int i = 0; i < 4; i++){
      float v = acc[nt][i] + b;
      if (doRelu) v = fmaxf(v, 0.f);
      outB[(row0 + wv*16 + q*4 + i)*256 + col] = f2bf(v);
    }
  }
}

// ---------------------------------------------------------------------------
// post_pass helpers (16 rows x 256 cols, 16 waves; wave wv owns nt = wv).
// ---------------------------------------------------------------------------
__device__ __forceinline__ void stage256(
    const unsigned short* __restrict__ inA,
    const unsigned short* __restrict__ wt, int tbase,
    const float* __restrict__ bias,
    unsigned short* __restrict__ outA, int lane, int wv)
{
  int q = lane >> 4, c16 = lane & 15;
  v8s wf[8];
  #pragma unroll
  for (int kt = 0; kt < 8; kt++) wf[kt] = LDB(tbase + wv*8 + kt);
  v8s af[8];
  #pragma unroll
  for (int kt = 0; kt < 8; kt++) af[kt] = *(const v8s*)&inA[c16*AB_S + kt*32 + q*8];
  f32x4 acc = (f32x4){0.f,0.f,0.f,0.f};
  #pragma unroll
  for (int kt = 0; kt < 8; kt++) acc = MFMA16(af[kt], wf[kt], acc);
  int col = wv*16 + c16;
  float b = bias[col];
  #pragma unroll
  for (int i = 0; i < 4; i++)
    outA[(q*4 + i)*AB_S + col] = f2bf(fmaxf(acc[i] + b, 0.f));
}

__device__ __forceinline__ void pheads(
    const unsigned short* __restrict__ X2,
    const unsigned short* __restrict__ wt, int tM, int tV,
    const float* __restrict__ bM, const float* __restrict__ bV,
    float* __restrict__ muF, float* __restrict__ varF, int lane, int wv)
{
  int q = lane >> 4, c16 = lane & 15;
  int mtx = wv >> 3, nt = wv & 7;
  int tb  = mtx ? tV : tM;
  v8s wf[8];
  #pragma unroll
  for (int kt = 0; kt < 8; kt++) wf[kt] = LDB(tb + nt*8 + kt);
  v8s af[8];
  #pragma unroll
  for (int kt = 0; kt < 8; kt++) af[kt] = *(const v8s*)&X2[c16*AB_S + kt*32 + q*8];
  f32x4 acc = (f32x4){0.f,0.f,0.f,0.f};
  #pragma unroll
  for (int kt = 0; kt < 8; kt++) acc = MFMA16(af[kt], wf[kt], acc);
  int col = nt*16 + c16;
  float b = mtx ? bV[col] : bM[col];
  float* dst = mtx ? varF : muF;
  #pragma unroll
  for (int i = 0; i < 4; i++){
    float v = acc[i] + b;
    if (mtx) v = __expf(v) + 0.01f;
    dst[(q*4 + i)*LATN + col] = v;
  }
}

__device__ __forceinline__ void pstage_add(
    const unsigned short* __restrict__ inA,
    const unsigned short* __restrict__ wt, int tbase,
    const unsigned short* __restrict__ Pbuf, int row0,
    unsigned short* __restrict__ outA, int lane, int wv)
{
  int q = lane >> 4, c16 = lane & 15;
  v8s wf[8];
  #pragma unroll
  for (int kt = 0; kt < 8; kt++) wf[kt] = LDB(tbase + wv*8 + kt);
  v8s af[8];
  #pragma unroll
  for (int kt = 0; kt < 8; kt++) af[kt] = *(const v8s*)&inA[c16*AB_S + kt*32 + q*8];
  int col = wv*16 + c16;
  unsigned short pv[4];
  #pragma unroll
  for (int i = 0; i < 4; i++){
    int grow = row0 + q*4 + i;          // = b*127 + t
    int prow = grow + grow/127 + 1;     // = b*128 + (t+1)
    pv[i] = __builtin_nontemporal_load(&Pbuf[(size_t)prow*256 + col]);
  }
  f32x4 acc = (f32x4){0.f,0.f,0.f,0.f};
  #pragma unroll
  for (int kt = 0; kt < 8; kt++) acc = MFMA16(af[kt], wf[kt], acc);
  #pragma unroll
  for (int i = 0; i < 4; i++){
    float v = acc[i] + bf2f(pv[i]);
    outA[(q*4 + i)*AB_S + col] = f2bf(fmaxf(v, 0.f));
  }
}

// ---------------------------------------------------------------------------
// Group barrier: monotonic epoch counters, relaxed agent-scope atomics only.
// __syncthreads drains vmcnt(0) -> the write-through exchange stores are at
// the coherence point before tid0 increments; spinners poll relaxed; readers
// use coherent loads, so no acquire/invalidate is needed.
// ---------------------------------------------------------------------------
__device__ __forceinline__ void gsync(unsigned* c, unsigned tgt, int tid)
{
  __syncthreads();
  asm volatile("" ::: "memory");
  if (tid == 0){
    __hip_atomic_fetch_add(c, 1u, __ATOMIC_RELAXED, __HIP_MEMORY_SCOPE_AGENT);
    while (__hip_atomic_load(c, __ATOMIC_RELAXED, __HIP_MEMORY_SCOPE_AGENT) < tgt)
      __builtin_amdgcn_s_sleep(1);
  }
  asm volatile("" ::: "memory");
  __syncthreads();
}

// ---------------------------------------------------------------------------
// Distributed recurrence. Grid 256 = 32 groups x 8 members; group g handles
// batch rows g*16..g*16+15; member j owns output cols [32j,32j+32) of every
// 256-wide stage and latent cols [16j,16j+16) of the heads. 128 threads =
// 2 waves; wave wv owns ntile 2j+wv.
// ---------------------------------------------------------------------------
struct RnnArgs {
  const unsigned short *wt, *Pbuf;
  const float *actions, *noise, *w_gin, *b_gin, *b_ih, *b_hh, *b_po2, *b_pom, *b_pov;
  unsigned short *Hb, *XS, *XG, *XH, *XM1, *XM2;
  unsigned *cnt;
  float *out;
};

__global__ __launch_bounds__(128, 1) void rssm_rnn(RnnArgs A)
{
  __shared__ unsigned short Lw[NLT*512];     // 139264 B weight slices
  __shared__ float LwaA[256];                // w_gin action part [32 cols][8]
  __shared__ float Lbg[32], Lbih[96], Lbhh[96], Lbp2[32], Lbm[16], Lbv[16];
  __shared__ float muv[2][16][16];
  __shared__ float aF[128];

  int tid = threadIdx.x, lane = tid & 63, wv = tid >> 6;
  int q = lane >> 4, c16 = lane & 15;
  int g = blockIdx.x & 31, j = blockIdx.x >> 5;
  int b0 = g * 16;
  int lc = wv*16 + c16;          // local col in the 32-wide slice
  int gc = 32*j + lc;            // global col

  // ---- pin weight slices in LDS ----
  for (int u = tid; u < NLT*64; u += 128){
    int lt = u >> 6, ch = u & 63;
    int gt;
    if (lt < 8){
      int w = lt >> 2, kt = lt & 3;
      gt = GINS_T + (2*j + w)*4 + kt;
    } else if (lt < 56){
      int u2 = lt - 8;
      gt = IH_T + ((u2 >> 4)*16 + 2*j + ((u2 >> 3) & 1))*8 + (u2 & 7);
    } else if (lt < 104){
      int u2 = lt - 56;
      gt = HH_T + ((u2 >> 4)*16 + 2*j + ((u2 >> 3) & 1))*8 + (u2 & 7);
    } else if (lt < 120){
      int u2 = lt - 104;
      gt = PO1H_T + (2*j + (u2 >> 3))*8 + (u2 & 7);
    } else {
      int u2 = lt - 120;
      gt = PO2_T + (2*j + (u2 >> 3))*8 + (u2 & 7);
    }
    *(v8s*)&Lw[lt*512 + ch*8] = *(const v8s*)(A.wt + (size_t)gt*512 + ch*8);
  }
  for (int u = tid; u < 256; u += 128)
    LwaA[u] = A.w_gin[(size_t)(32*j + (u >> 3))*136 + 128 + (u & 7)];
  if (tid < 32){ Lbg[tid] = A.b_gin[32*j + tid]; Lbp2[tid] = A.b_po2[32*j + tid]; }
  if (tid >= 32 && tid < 128){
    int u = tid - 32;
    if (u < 96){
      Lbih[u] = A.b_ih[(u >> 5)*256 + 32*j + (u & 31)];
      Lbhh[u] = A.b_hh[(u >> 5)*256 + 32*j + (u & 31)];
    }
  }
  if (tid < 16){ Lbm[tid] = A.b_pom[16*j + tid]; Lbv[tid] = A.b_pov[16*j + tid]; }

  v8s wh[8];   // head weights persistent in registers (wave0: pom, wave1: pov)
  {
    const unsigned short* wt = A.wt;
    int tb = (wv ? POV_T : POM_T) + j*8;
    #pragma unroll
    for (int kt = 0; kt < 8; kt++) wh[kt] = LDB(tb + kt);
  }
  float hFr[4] = {0.f, 0.f, 0.f, 0.f};   // f32 h carry, rows q*4+i, col gc
  __syncthreads();

  unsigned* cS  = A.cnt + g*16 + 0;
  unsigned* cG  = A.cnt + g*16 + 1;
  unsigned* cH  = A.cnt + g*16 + 2;
  unsigned* cM1 = A.cnt + g*16 + 3;
  unsigned* cM2 = A.cnt + g*16 + 4;
  const size_t sl = (size_t)(g*8);   // slice index base for this group

  for (int t = -1; t < TN-1; t++){
    unsigned e2 = (unsigned)(8*(t+2));
    if (t >= 0){
      aF[tid] = __builtin_nontemporal_load(
          &A.actions[((size_t)(b0 + (tid >> 3))*127 + t)*8 + (tid & 7)]);
      __syncthreads();
      // ---- gin: g = relu(s @ WginS^T + a @ WginA^T + b_gin) ----
      {
        v8s af4[4], wf[4];
        #pragma unroll
        for (int kt = 0; kt < 4; kt++)
          af4[kt] = ldx16(A.XS + ((sl + 2*kt + (q >> 1))*16 + c16)*16 + (q & 1)*8);
        #pragma unroll
        for (int kt = 0; kt < 4; kt++)
          wf[kt] = *(const v8s*)&Lw[(GIN_L + wv*4 + kt)*512 + lane*8];
        f32x4 acc = (f32x4){0.f,0.f,0.f,0.f};
        #pragma unroll
        for (int kt = 0; kt < 4; kt++) acc = MFMA16(af4[kt], wf[kt], acc);
        float bg = Lbg[lc];
        #pragma unroll
        for (int i = 0; i < 4; i++){
          int r = q*4 + i;
          float v = acc[i] + bg;
          #pragma unroll
          for (int m = 0; m < 8; m++) v += aF[r*8 + m]*LwaA[lc*8 + m];
          stxs(&A.XG[((sl + j)*16 + r)*32 + lc], f2bf(fmaxf(v, 0.f)));
        }
      }
      gsync(cG, (unsigned)(8*(t+1)), tid);
      // ---- GRU ----
      {
        int p = t & 1;
        v8s ag[8], ah[8];
        #pragma unroll
        for (int kt = 0; kt < 8; kt++){
          ag[kt] = ldx16(A.XG + ((sl + kt)*16 + c16)*32 + q*8);
          ah[kt] = ldx16(A.XH + (((size_t)p*256 + sl + kt)*16 + c16)*32 + q*8);
        }
        f32x4 accI[3];
        #pragma unroll
        for (int x = 0; x < 3; x++){
          v8s wf[8];
          #pragma unroll
          for (int kt = 0; kt < 8; kt++)
            wf[kt] = *(const v8s*)&Lw[(IH_L + (x*2 + wv)*8 + kt)*512 + lane*8];
          accI[x] = (f32x4){0.f,0.f,0.f,0.f};
          #pragma unroll
          for (int kt = 0; kt < 8; kt++) accI[x] = MFMA16(ag[kt], wf[kt], accI[x]);
        }
        float rg[4], zg[4];
        {
          v8s wf[8];
          #pragma unroll
          for (int kt = 0; kt < 8; kt++)
            wf[kt] = *(const v8s*)&Lw[(HH_L + (0*2 + wv)*8 + kt)*512 + lane*8];
          f32x4 a = (f32x4){0.f,0.f,0.f,0.f};
          #pragma unroll
          for (int kt = 0; kt < 8; kt++) a = MFMA16(ah[kt], wf[kt], a);
          float bir = Lbih[lc], bhr = Lbhh[lc];
          #pragma unroll
          for (int i = 0; i < 4; i++) rg[i] = sigm(accI[0][i] + bir + a[i] + bhr);
        }
        {
          v8s wf[8];
          #pragma unroll
          for (int kt = 0; kt < 8; kt++)
            wf[kt] = *(const v8s*)&Lw[(HH_L + (1*2 + wv)*8 + kt)*512 + lane*8];
          f32x4 a = (f32x4){0.f,0.f,0.f,0.f};
          #pragma unroll
          for (int kt = 0; kt < 8; kt++) a = MFMA16(ah[kt], wf[kt], a);
          float biz = Lbih[32 + lc], bhz = Lbhh[32 + lc];
          #pragma unroll
          for (int i = 0; i < 4; i++) zg[i] = sigm(accI[1][i] + biz + a[i] + bhz);
        }
        {
          v8s wf[8];
          #pragma unroll
          for (int kt = 0; kt < 8; kt++)
            wf[kt] = *(const v8s*)&Lw[(HH_L + (2*2 + wv)*8 + kt)*512 + lane*8];
          f32x4 a = (f32x4){0.f,0.f,0.f,0.f};
          #pragma unroll
          for (int kt = 0; kt < 8; kt++) a = MFMA16(ah[kt], wf[kt], a);
          float bin = Lbih[64 + lc], bhn = Lbhh[64 + lc];
          #pragma unroll
          for (int i = 0; i < 4; i++){
            int r = q*4 + i;
            float ng = tanhx(accI[2][i] + bin + rg[i]*(a[i] + bhn));
            float hv = (1.f - zg[i])*ng + zg[i]*hFr[i];
            hFr[i] = hv;
            unsigned short hb = f2bf(hv);
            stxs(&A.XH[(((size_t)(1 - p)*256 + sl + j)*16 + r)*32 + lc], hb);
            __builtin_nontemporal_store(hb, &A.Hb[((size_t)(b0 + r)*127 + t)*256 + gc]);
          }
        }
      }
      gsync(cH, (unsigned)(8*(t+1)), tid);
      // ---- po1h -> m1 ----
      {
        int p = t & 1;
        v8s ah[8], wf[8];
        #pragma unroll
        for (int kt = 0; kt < 8; kt++)
          ah[kt] = ldx16(A.XH + (((size_t)(1 - p)*256 + sl + kt)*16 + c16)*32 + q*8);
        #pragma unroll
        for (int kt = 0; kt < 8; kt++)
          wf[kt] = *(const v8s*)&Lw[(P1_L + wv*8 + kt)*512 + lane*8];
        unsigned short pv[4];
        #pragma unroll
        for (int i = 0; i < 4; i++)
          pv[i] = __builtin_nontemporal_load(
              &A.Pbuf[((size_t)(b0 + q*4 + i)*TN + (t+1))*256 + gc]);
        f32x4 acc = (f32x4){0.f,0.f,0.f,0.f};
        #pragma unroll
        for (int kt = 0; kt < 8; kt++) acc = MFMA16(ah[kt], wf[kt], acc);
        #pragma unroll
        for (int i = 0; i < 4; i++)
          stxs(&A.XM1[((sl + j)*16 + q*4 + i)*32 + lc],
               f2bf(fmaxf(acc[i] + bf2f(pv[i]), 0.f)));
      }
    } else {
      // ---- prologue: m1 = relu(po1_o[:, t=0]) (belief = 0) ----
      #pragma unroll
      for (int i = 0; i < 4; i++){
        int r = q*4 + i;
        unsigned short pv = __builtin_nontemporal_load(
            &A.Pbuf[((size_t)(b0 + r)*TN + 0)*256 + gc]);
        stxs(&A.XM1[((sl + j)*16 + r)*32 + lc], f2bf(fmaxf(bf2f(pv), 0.f)));
      }
    }
    gsync(cM1, e2, tid);
    // ---- po2 -> m2 ----
    {
      v8s am[8], wf[8];
      #pragma unroll
      for (int kt = 0; kt < 8; kt++)
        am[kt] = ldx16(A.XM1 + ((sl + kt)*16 + c16)*32 + q*8);
      #pragma unroll
      for (int kt = 0; kt < 8; kt++)
        wf[kt] = *(const v8s*)&Lw[(P2_L + wv*8 + kt)*512 + lane*8];
      f32x4 acc = (f32x4){0.f,0.f,0.f,0.f};
      #pragma unroll
      for (int kt = 0; kt < 8; kt++) acc = MFMA16(am[kt], wf[kt], acc);
      #pragma unroll
      for (int i = 0; i < 4; i++)
        stxs(&A.XM2[((sl + j)*16 + q*4 + i)*32 + lc],
             f2bf(fmaxf(acc[i] + Lbp2[lc], 0.f)));
    }
    gsync(cM2, e2, tid);
    // ---- heads (wave0: mu, wave1: var) ----
    {
      v8s am[8];
      #pragma unroll
      for (int kt = 0; kt < 8; kt++)
        am[kt] = ldx16(A.XM2 + ((sl + kt)*16 + c16)*32 + q*8);
      f32x4 acc = (f32x4){0.f,0.f,0.f,0.f};
      #pragma unroll
      for (int kt = 0; kt < 8; kt++) acc = MFMA16(am[kt], wh[kt], acc);
      #pragma unroll
      for (int i = 0; i < 4; i++){
        float v = acc[i] + (wv ? Lbv[c16] : Lbm[c16]);
        if (wv) v = __expf(v) + 0.01f;
        muv[wv][q*4 + i][c16] = v;
      }
    }
    __syncthreads();
    // ---- sample: s = mu + sqrt(var)*eps ----
    for (int u = tid; u < 256; u += 128){
      int r = u >> 4, c = u & 15;
      float mq = muv[0][r][c], vq = muv[1][r][c];
      float ep = __builtin_nontemporal_load(
          &A.noise[((size_t)(t+1)*BN + b0 + r)*LATN + 16*j + c]);
      float sv = mq + sqrtf(vq)*ep;
      __builtin_nontemporal_store(sv, &A.out[((size_t)(b0 + r)*TN + (t+1))*LATN + 16*j + c]);
      stxs(&A.XS[(sl + j)*256 + r*16 + c], f2bf(sv));
    }
    gsync(cS, e2, tid);
  }
}

// ---------------------------------------------------------------------------
// Parallel post-pass over all (b,t) rows: prior + posterior + KL.
// ---------------------------------------------------------------------------
__global__ __launch_bounds__(1024, 4) void post_pass(
    const unsigned short* __restrict__ wt,
    const unsigned short* __restrict__ Pbuf,
    const unsigned short* __restrict__ Hb,
    const float* __restrict__ b_pr1, const float* __restrict__ b_pr2,
    const float* __restrict__ b_prm, const float* __restrict__ b_prv,
    const float* __restrict__ b_po2, const float* __restrict__ b_pom,
    const float* __restrict__ b_pov,
    float* __restrict__ out)
{
  __shared__ unsigned short hC[16*AB_S];
  __shared__ unsigned short X1[16*AB_S];
  __shared__ unsigned short X2[16*AB_S];
  __shared__ float mupF[16*LATN], varpF[16*LATN];
  __shared__ float muqF[16*LATN], varqF[16*LATN];

  int tid = threadIdx.x, lane = tid & 63, wv = tid >> 6;
  int row0 = blockIdx.x * 16;

  if (tid < 512){
    int r = tid >> 5, c8 = (tid & 31)*8;
    *(v8s*)&hC[r*AB_S + c8] = *(const v8s*)&Hb[(size_t)(row0 + r)*256 + c8];
  }
  __syncthreads();

  stage256(hC, wt, PR1_T, b_pr1, X1, lane, wv);
  __syncthreads();
  stage256(X1, wt, PR2_T, b_pr2, X2, lane, wv);
  __syncthreads();
  pheads(X2, wt, PRM_T, PRV_T, b_prm, b_prv, mupF, varpF, lane, wv);
  __syncthreads();

  pstage_add(hC, wt, PO1H_T, Pbuf, row0, X1, lane, wv);
  __syncthreads();
  stage256(X1, wt, PO2_T, b_po2, X2, lane, wv);
  __syncthreads();
  pheads(X2, wt, POM_T, POV_T, b_pom, b_pov, muqF, varqF, lane, wv);
  __syncthreads();

  {
    int r = wv;
    float kv = 0.f;
    #pragma unroll
    for (int ii = 0; ii < 2; ii++){
      int c = lane + ii*64;
      float mq = muqF[r*LATN + c], vq = varqF[r*LATN + c];
      float mp = mupF[r*LATN + c], vp = varpF[r*LATN + c];
      float d = mq - mp;
      kv += __logf(vp) - __logf(vq) + (vq + d*d)/vp - 1.f;
    }
    #pragma unroll
    for (int m = 1; m < 64; m <<= 1) kv += __shfl_xor(kv, m, 64);
    if (lane == 0)
      __builtin_nontemporal_store(0.5f*kv, &out[KL_OFF + (size_t)(row0 + r)]);
  }
}

// ---------------------------------------------------------------------------
extern "C" void kernel_launch(void* const* d_in, const int* in_sizes, int n_in,
                              void* d_out, int out_size, void* d_ws, size_t ws_size,
                              hipStream_t stream)
{
  (void)in_sizes; (void)n_in; (void)out_size; (void)ws_size;
  const float* vis    = (const float*)d_in[0];
  const float* acts   = (const float*)d_in[1];
  const float* noise  = (const float*)d_in[2];
  const float* w_obs1 = (const float*)d_in[3];
  const float* b_obs1 = (const float*)d_in[4];
  const float* w_obs2 = (const float*)d_in[5];
  const float* b_obs2 = (const float*)d_in[6];
  const float* w_gin  = (const float*)d_in[7];
  const float* b_gin  = (const float*)d_in[8];
  const float* w_ih   = (const float*)d_in[9];
  const float* w_hh   = (const float*)d_in[10];
  const float* b_ih   = (const float*)d_in[11];
  const float* b_hh   = (const float*)d_in[12];
  const float* w_pr1  = (const float*)d_in[13];
  const float* b_pr1  = (const float*)d_in[14];
  const float* w_pr2  = (const float*)d_in[15];
  const float* b_pr2  = (const float*)d_in[16];
  const float* w_prm  = (const float*)d_in[17];
  const float* b_prm  = (const float*)d_in[18];
  const float* w_prv  = (const float*)d_in[19];
  const float* b_prv  = (const float*)d_in[20];
  const float* w_po1  = (const float*)d_in[21];
  const float* b_po1  = (const float*)d_in[22];
  const float* w_po2  = (const float*)d_in[23];
  const float* b_po2  = (const float*)d_in[24];
  const float* w_pom  = (const float*)d_in[25];
  const float* b_pom  = (const float*)d_in[26];
  const float* w_pov  = (const float*)d_in[27];
  const float* b_pov  = (const float*)d_in[28];

  unsigned short* B1 = (unsigned short*)d_ws;                       // 65536x256 bf16
  unsigned short* WT = (unsigned short*)((char*)d_ws + B1_BYTES);   // shuffled tiles
  unsigned short* Hb  = WT + (size_t)TOT_TILES*512;                 // h_t (B*127 x 256)
  unsigned short* XS  = Hb + (size_t)BN*127*256;                    // s slices
  unsigned short* XG  = XS + 32*8*256;
  unsigned short* XH  = XG + 32*8*512;
  unsigned short* XM1 = XH + (size_t)2*32*8*512;
  unsigned short* XM2 = XM1 + 32*8*512;
  unsigned*       CNT = (unsigned*)(XM2 + 32*8*512);

  ShufArgs sa;
  const float* srcs[14] = {w_obs1, w_obs2, w_po1, w_po1, w_gin, w_ih, w_hh,
                           w_pr1, w_pr2, w_prm, w_prv, w_po2, w_pom, w_pov};
  const int strides[14] = {512,256,512,512,136,256,256,256,256,256,256,256,256,256};
  const int coloffs[14] = {0,0,256,0,0,0,0,0,0,0,0,0,0,0};
  const int ktl[14]     = {16,8,8,8,4,8,8,8,8,8,8,8,8,8};
  const int tbas[14]    = {OBS1_T,OBS2_T,PO1O_T,PO1H_T,GINS_T,IH_T,HH_T,
                           PR1_T,PR2_T,PRM_T,PRV_T,PO2_T,POM_T,POV_T};
  const int tcnt[14]    = {256,128,128,128,64,384,384,128,128,64,64,128,64,64};
  for (int i = 0; i < 14; i++){
    sa.src[i] = srcs[i]; sa.stride[i] = strides[i]; sa.coloff[i] = coloffs[i];
    sa.ktiles[i] = ktl[i]; sa.tbase[i] = tbas[i]; sa.tcnt[i] = tcnt[i];
  }
  shuffle_w<<<TOT_TILES, 64, 0, stream>>>(sa, WT);

  // obs MLP + po1_o, all in-place in B1 (rows are block-exclusive)
  big_gemm<<<1024, 256, 0, stream>>>(vis, 1, 512, WT, OBS1_T, b_obs1, 1, B1);
  big_gemm<<<1024, 256, 0, stream>>>(B1,  0, 256, WT, OBS2_T, b_obs2, 1, B1);
  big_gemm<<<1024, 256, 0, stream>>>(B1,  0, 256, WT, PO1O_T, b_po1,  0, B1);

  // zero H parity buffers + barrier counters (replayed each graph run)
  hipMemsetAsync(XH, 0, (size_t)2*32*8*512*2, stream);
  hipMemsetAsync(CNT, 0, 32*16*4, stream);

  RnnArgs ra;
  ra.wt = WT; ra.Pbuf = B1;
  ra.actions = acts; ra.noise = noise; ra.w_gin = w_gin;
  ra.b_gin = b_gin; ra.b_ih = b_ih; ra.b_hh = b_hh;
  ra.b_po2 = b_po2; ra.b_pom = b_pom; ra.b_pov = b_pov;
  ra.Hb = Hb; ra.XS = XS; ra.XG = XG; ra.XH = XH; ra.XM1 = XM1; ra.XM2 = XM2;
  ra.cnt = CNT; ra.out = (float*)d_out;
  rssm_rnn<<<256, 128, 0, stream>>>(ra);

  post_pass<<<4064, 1024, 0, stream>>>(WT, B1, Hb, b_pr1, b_pr2, b_prm, b_prv,
                                       b_po2, b_pom, b_pov, (float*)d_out);
}